// Round 1
// 1050.982 us; speedup vs baseline: 1.0845x; 1.0845x over previous
//
#include <hip/hip_runtime.h>
#include <cstddef>
#include <cstdint>

#define BN_EPS 1e-5f

typedef float f4 __attribute__((ext_vector_type(4)));
typedef _Float16 h2 __attribute__((ext_vector_type(2)));
typedef _Float16 h8 __attribute__((ext_vector_type(8)));

#if defined(__has_builtin)
#if __has_builtin(__builtin_amdgcn_fdot2)
#define DOT2(a, b, c) __builtin_amdgcn_fdot2((a), (b), (c), false)
#endif
#endif
#ifndef DOT2
#define DOT2(a, b, c) fmaf((float)(a)[1], (float)(b)[1], fmaf((float)(a)[0], (float)(b)[0], (c)))
#endif

// ---------------------------------------------------------------------------
// fp32 weight transpose (sconv0 only): W[27][CIN][COUT] -> Wt[k][ci/4][co][4]
// ---------------------------------------------------------------------------
template<int CIN, int COUT>
__global__ __launch_bounds__(256)
void wtrans(const float* __restrict__ W, float* __restrict__ Wt)
{
    const int t = blockIdx.x * 256 + threadIdx.x;
    constexpr int TOTAL = 27 * (CIN / 4) * COUT;
    if (t >= TOTAL) return;
    const int co = t % COUT;
    const int rest = t / COUT;
    const int c4 = rest % (CIN / 4);
    const int k  = rest / (CIN / 4);
    f4 v;
    #pragma unroll
    for (int u = 0; u < 4; ++u)
        v[u] = W[((size_t)k * CIN + c4 * 4 + u) * COUT + co];
    *(f4*)(Wt + (size_t)t * 4) = v;
}

// ---------------------------------------------------------------------------
// f16 weight transpose: W[27][CIN][COUT] -> Wh[k][ci/8][co][8]
// ---------------------------------------------------------------------------
template<int CIN, int COUT>
__global__ __launch_bounds__(256)
void wtrans_h(const float* __restrict__ W, _Float16* __restrict__ Wh)
{
    const int t = blockIdx.x * 256 + threadIdx.x;
    constexpr int TOTAL = 27 * (CIN / 8) * COUT;
    if (t >= TOTAL) return;
    const int co = t % COUT;
    const int rest = t / COUT;
    const int t8 = rest % (CIN / 8);
    const int k  = rest / (CIN / 8);
    h8 v;
    #pragma unroll
    for (int u = 0; u < 8; ++u)
        v[u] = (_Float16)W[((size_t)k * CIN + t8 * 8 + u) * COUT + co];
    *(h8*)(Wh + (size_t)t * 8) = v;
}

// ---------------------------------------------------------------------------
// Map transpose: map[27][Nout] -> mapT[Nout][32] (k-major per row, -1 pad).
// ---------------------------------------------------------------------------
__global__ __launch_bounds__(256)
void map_transpose(const int* __restrict__ map, int Nout,
                   int* __restrict__ mapT)
{
    __shared__ int s[256][28];
    const int tid  = threadIdx.x;
    const int base = blockIdx.x * 256;
    const int j    = base + tid;
    for (int k = 0; k < 27; ++k)
        s[tid][k] = (j < Nout) ? map[(size_t)k * Nout + j] : -1;
    __syncthreads();
    for (int i = tid; i < 256 * 32; i += 256) {
        const int r = i >> 5, c = i & 31;
        if (base + r < Nout)
            mapT[(size_t)(base + r) * 32 + c] = (c < 27) ? s[r][c] : -1;
    }
}

// ---------------------------------------------------------------------------
// R=1 f16 sparse conv (SPARSE maps): one wave = one row.
// ---------------------------------------------------------------------------
template<int CIN, int CINA, int COUT>
__global__ __launch_bounds__(256)
void sconv_r1(const _Float16* __restrict__ xA, const _Float16* __restrict__ xB,
              const _Float16* __restrict__ Wh, const int* __restrict__ mapT,
              int Nout, _Float16* __restrict__ out)
{
    constexpr int CINB = CIN - CINA;
    constexpr int CPL  = COUT / 64;
    constexpr int NT   = CIN / 8;
    const int lane = threadIdx.x & 63;
    const int j    = blockIdx.x * 4 + (threadIdx.x >> 6);

    int mk = -1;
    if (j < Nout && lane < 32) mk = mapT[(size_t)j * 32 + lane];
    unsigned long long act = __ballot(mk >= 0);   // bits 0..26 only

    float acc[CPL];
    #pragma unroll
    for (int c = 0; c < CPL; ++c) acc[c] = 0.f;

    while (act) {
        const int k = (int)__builtin_ctzll(act);
        act &= act - 1;
        const int m = __builtin_amdgcn_readlane(mk, k);   // uniform SGPR

        const _Float16* pA = xA + (size_t)m * CINA;
        const _Float16* pB = nullptr;
        if constexpr (CINB > 0) pB = xB + (size_t)m * CINB;

        const _Float16* Wk = Wh + (size_t)k * NT * COUT * 8;

        #pragma unroll
        for (int t = 0; t < NT; ++t) {
            const int ci = t * 8;
            h8 wv[CPL];
            #pragma unroll
            for (int c = 0; c < CPL; ++c)
                wv[c] = *(const h8*)(Wk + ((size_t)t * COUT + c * 64 + lane) * 8);
            const _Float16* p;
            if constexpr (CINB > 0)
                p = (ci < CINA) ? (pA + ci) : (pB + (ci - CINA));
            else
                p = pA + ci;
            const h8 xv = *(const h8*)p;
            const h2* xp = (const h2*)&xv;
            #pragma unroll
            for (int q = 0; q < 4; ++q) {
                #pragma unroll
                for (int c = 0; c < CPL; ++c) {
                    const h2* wp = (const h2*)&wv[c];
                    acc[c] = DOT2(xp[q], wp[q], acc[c]);
                }
            }
        }
    }

    if (j < Nout) {
        #pragma unroll
        for (int c = 0; c < CPL; ++c)
            out[(size_t)j * COUT + c * 64 + lane] = (_Float16)acc[c];
    }
}

// ---------------------------------------------------------------------------
// R-rows/wave f16 sparse conv (DENSE/MID/SPARSE maps), loop inversion:
// per active k (union over R rows), the ENTIRE W k-slice is preloaded into
// registers (NT*CPL h8), then rows loop OUTSIDE the tile loop: ONE uniform
// guard per row, batched x s_loads inside the guard, then the dot2 block.
// W traffic per row drops ~R/union_blowup vs the r1 kernel.
// ---------------------------------------------------------------------------
template<int CIN, int CINA, int COUT, int R>
__global__ __launch_bounds__(256)
void sconv_big_h(const _Float16* __restrict__ xA, const _Float16* __restrict__ xB,
                 const _Float16* __restrict__ Wh, const int* __restrict__ map,
                 int Nout, _Float16* __restrict__ out)
{
    constexpr int CINB = CIN - CINA;
    constexpr int CPL  = COUT / 64;
    constexpr int NT   = CIN / 8;
    const int lane = threadIdx.x & 63;
    const int wave = threadIdx.x >> 6;
    const int row0 = (blockIdx.x * 4 + wave) * R;

    int mk[R];
    bool anyv = false;
    #pragma unroll
    for (int r = 0; r < R; ++r) {
        const int j = row0 + r;
        mk[r] = (lane < 27 && j < Nout) ? map[(size_t)lane * Nout + j] : -1;
        anyv |= (mk[r] >= 0);
    }
    unsigned long long act = __ballot(anyv);

    float acc[R][CPL];
    #pragma unroll
    for (int r = 0; r < R; ++r)
        #pragma unroll
        for (int c = 0; c < CPL; ++c) acc[r][c] = 0.f;

    while (act) {
        const int k = (int)__builtin_ctzll(act);
        act &= act - 1;

        // ---- preload the full W k-slice into registers ----
        const _Float16* Wk = Wh + (size_t)k * NT * COUT * 8;
        h8 wv[NT][CPL];
        #pragma unroll
        for (int t = 0; t < NT; ++t)
            #pragma unroll
            for (int c = 0; c < CPL; ++c)
                wv[t][c] = *(const h8*)(Wk + ((size_t)t * COUT + c * 64 + lane) * 8);

        // ---- per row: one guard, batched s_loads, dot2 block ----
        #pragma unroll
        for (int r = 0; r < R; ++r) {
            const int m = __builtin_amdgcn_readlane(mk[r], k);  // uniform SGPR
            if (m >= 0) {
                h8 xv[NT];
                #pragma unroll
                for (int t = 0; t < NT; ++t) {
                    const int ci = t * 8;
                    const _Float16* p;
                    if constexpr (CINB > 0)
                        p = (ci < CINA) ? (xA + (size_t)m * CINA + ci)
                                        : (xB + (size_t)m * CINB + (ci - CINA));
                    else
                        p = xA + (size_t)m * CINA + ci;
                    xv[t] = *(const h8*)p;
                }
                #pragma unroll
                for (int t = 0; t < NT; ++t) {
                    const h2* xp = (const h2*)&xv[t];
                    #pragma unroll
                    for (int q = 0; q < 4; ++q) {
                        #pragma unroll
                        for (int c = 0; c < CPL; ++c) {
                            const h2* wp = (const h2*)&wv[t][c];
                            acc[r][c] = DOT2(xp[q], wp[q], acc[r][c]);
                        }
                    }
                }
            }
        }
    }

    #pragma unroll
    for (int r = 0; r < R; ++r) {
        const int j = row0 + r;
        if (j < Nout) {
            #pragma unroll
            for (int c = 0; c < CPL; ++c)
                out[(size_t)j * COUT + c * 64 + lane] = (_Float16)acc[r][c];
        }
    }
}

// ---------------------------------------------------------------------------
// conv0: CIN=16 (fp32 feats), COUT=32 -> half out. 2 rows/wave, ctz-union.
// ---------------------------------------------------------------------------
__global__ __launch_bounds__(256)
void sconv0(const float* __restrict__ x, const float* __restrict__ Wt,
            const int* __restrict__ map, int N, _Float16* __restrict__ out,
            const float* __restrict__ zrow)
{
    const int tid  = threadIdx.x;
    const int lane = tid & 63;
    const int l32  = tid & 31;
    const int co   = l32;
    const int j    = blockIdx.x * 8 + (tid >> 5);

    int mk = (l32 < 27 && j < N) ? map[(size_t)l32 * N + j] : -1;
    const unsigned long long bal = __ballot(mk >= 0);
    unsigned int act = (unsigned int)((bal | (bal >> 32)) & 0x7FFFFFFu);

    float a0 = 0.f, a1 = 0.f, a2 = 0.f, a3 = 0.f;
    while (act) {
        const int k = (int)__builtin_ctz(act);
        act &= act - 1;
        const int m = __shfl(mk, (lane & 32) + k);
        const float* xr = (m >= 0) ? (x + (size_t)m * 16) : zrow;
        const float* wk = Wt + (size_t)k * 16 * 32;
        f4 w0 = *(const f4*)(wk + (0 * 32 + co) * 4);
        f4 w1 = *(const f4*)(wk + (1 * 32 + co) * 4);
        f4 w2 = *(const f4*)(wk + (2 * 32 + co) * 4);
        f4 w3 = *(const f4*)(wk + (3 * 32 + co) * 4);
        f4 x0 = *(const f4*)(xr);
        f4 x1 = *(const f4*)(xr + 4);
        f4 x2 = *(const f4*)(xr + 8);
        f4 x3 = *(const f4*)(xr + 12);
        #pragma unroll
        for (int u = 0; u < 4; ++u) {
            a0 = fmaf(x0[u], w0[u], a0);
            a1 = fmaf(x1[u], w1[u], a1);
            a2 = fmaf(x2[u], w2[u], a2);
            a3 = fmaf(x3[u], w3[u], a3);
        }
    }
    if (j < N) out[(size_t)j * 32 + co] = (_Float16)((a0 + a1) + (a2 + a3));
}

// ---------------------------------------------------------------------------
// conv0t: concat(d1[*,64]h, s1[*,32]h) -> out[N0,2] fp32. ctz-union loop.
// ---------------------------------------------------------------------------
__global__ __launch_bounds__(256)
void sconv0t(const _Float16* __restrict__ d1, const _Float16* __restrict__ s1,
             const float* __restrict__ W /*[27,96,2]*/,
             const int* __restrict__ map, int N, float* __restrict__ out,
             const _Float16* __restrict__ zrh)
{
    const int tid  = threadIdx.x;
    const int lane = tid & 63;
    const int l32  = tid & 31;
    const int j    = blockIdx.x * 8 + (tid >> 5);

    int mk = (l32 < 27 && j < N) ? map[(size_t)l32 * N + j] : -1;
    const unsigned long long bal = __ballot(mk >= 0);
    unsigned int act = (unsigned int)((bal | (bal >> 32)) & 0x7FFFFFFu);

    float a0 = 0.f, a1 = 0.f;
    while (act) {
        const int k = (int)__builtin_ctz(act);
        act &= act - 1;
        const int m = __shfl(mk, (lane & 32) + k);
        const _Float16* p1 = (m >= 0) ? (d1 + (size_t)m * 64) : zrh;
        const _Float16* p2 = (m >= 0) ? (s1 + (size_t)m * 32) : zrh;
        const float* w = W + (size_t)k * 96 * 2;
        const float x0 = (float)p1[l32];
        const float x1 = (float)p1[l32 + 32];
        const float x2 = (float)p2[l32];
        a0 = fmaf(x0, w[l32 * 2 + 0], a0);
        a1 = fmaf(x0, w[l32 * 2 + 1], a1);
        a0 = fmaf(x1, w[(l32 + 32) * 2 + 0], a0);
        a1 = fmaf(x1, w[(l32 + 32) * 2 + 1], a1);
        a0 = fmaf(x2, w[(l32 + 64) * 2 + 0], a0);
        a1 = fmaf(x2, w[(l32 + 64) * 2 + 1], a1);
    }
    #pragma unroll
    for (int off = 1; off < 32; off <<= 1) {
        a0 += __shfl_xor(a0, off, 32);
        a1 += __shfl_xor(a1, off, 32);
    }
    if (l32 == 0 && j < N) {
        out[(size_t)j * 2 + 0] = a0;
        out[(size_t)j * 2 + 1] = a1;
    }
}

// ---------------------------------------------------------------------------
// BN pass 1 on half tensors
// ---------------------------------------------------------------------------
template<int C>
__global__ __launch_bounds__(256)
void bn_reduce_h(const _Float16* __restrict__ x, int N,
                 float* __restrict__ sums)
{
    constexpr int RG = 256 / C;
    const int tid = threadIdx.x;
    const int c   = tid % C;
    const int rg  = tid / C;
    float s = 0.f, s2 = 0.f;
    for (int j = blockIdx.x * RG + rg; j < N; j += gridDim.x * RG) {
        const float v = (float)x[(size_t)j * C + c];
        s += v;
        s2 += v * v;
    }
    __shared__ float sh[2 * 256];
    sh[tid] = s;
    sh[256 + tid] = s2;
    __syncthreads();
    for (int stride = 128; stride >= C; stride >>= 1) {
        if (tid < stride) {
            sh[tid] += sh[tid + stride];
            sh[256 + tid] += sh[256 + tid + stride];
        }
        __syncthreads();
    }
    if (tid < C) {
        atomicAdd(&sums[c], sh[tid]);
        atomicAdd(&sums[C + c], sh[256 + tid]);
    }
}

// ---------------------------------------------------------------------------
// BN pass 2 on half tensors
// ---------------------------------------------------------------------------
template<int C>
__global__ __launch_bounds__(256)
void bn_apply_h(_Float16* __restrict__ x, int N,
                const float* __restrict__ sums,
                const float* __restrict__ g, const float* __restrict__ b)
{
    const int tid = blockIdx.x * blockDim.x + threadIdx.x;
    const int c = tid % C;
    const float invN = 1.0f / (float)N;
    const float mean = sums[c] * invN;
    float var = sums[C + c] * invN - mean * mean;
    var = fmaxf(var, 0.f);
    const float sc = g[c] * rsqrtf(var + BN_EPS);
    const float sh = b[c] - mean * sc;
    const int rows_stride = (gridDim.x * blockDim.x) / C;
    for (int j = tid / C; j < N; j += rows_stride) {
        const size_t i = (size_t)j * C + c;
        const float v = fmaf((float)x[i], sc, sh);
        x[i] = (_Float16)(v > 0.f ? v : 0.f);
    }
}

// ---------------------------------------------------------------------------
extern "C" void kernel_launch(void* const* d_in, const int* in_sizes, int n_in,
                              void* d_out, int out_size, void* d_ws, size_t ws_size,
                              hipStream_t stream)
{
    const float* feats = (const float*)d_in[0];
    const float* W0  = (const float*)d_in[1];
    const float* g0  = (const float*)d_in[2];
    const float* b0  = (const float*)d_in[3];
    const float* W1  = (const float*)d_in[4];
    const float* g1  = (const float*)d_in[5];
    const float* b1  = (const float*)d_in[6];
    const float* W2  = (const float*)d_in[7];
    const float* g2  = (const float*)d_in[8];
    const float* b2  = (const float*)d_in[9];
    const float* W2t = (const float*)d_in[10];
    const float* g2t = (const float*)d_in[11];
    const float* b2t = (const float*)d_in[12];
    const float* W1t = (const float*)d_in[13];
    const float* g1t = (const float*)d_in[14];
    const float* b1t = (const float*)d_in[15];
    const float* W0t = (const float*)d_in[16];
    const int* map0  = (const int*)d_in[17];
    const int* map1  = (const int*)d_in[18];
    const int* map2  = (const int*)d_in[19];
    const int* map2t = (const int*)d_in[20];
    const int* map1t = (const int*)d_in[21];
    const int* map0t = (const int*)d_in[22];

    const int N0 = in_sizes[0] / 16;
    const int N1 = in_sizes[18] / 27;
    const int N2 = in_sizes[19] / 27;

    float* ws = (float*)d_ws;
    float* sums  = ws;          // 704 floats of BN accumulators
    float* sums0 = sums;        // 2*32
    float* sums1 = sums + 64;   // 2*64
    float* sums2 = sums + 192;  // 2*128
    float* sums3 = sums + 448;  // 2*64
    float* sums4 = sums + 576;  // 2*64
    float* zrow  = sums + 704;  // 128 zeroed floats (fp32 & f16 zero rows)
    float* Wt0   = zrow + 128;  // 27*16*32 fp32
    _Float16* hb = (_Float16*)(Wt0 + 27 * 16 * 32);
    _Float16* Wh1  = hb;                        // 27*32*64
    _Float16* Wh2  = Wh1 + 27 * 32 * 64;        // 27*64*128
    _Float16* Wh2t = Wh2 + 27 * 64 * 128;       // 27*128*64
    _Float16* Wh1t = Wh2t + 27 * 128 * 64;      // 27*128*64
    _Float16* y0 = Wh1t + 27 * 128 * 64;        // [N0,32]  s1
    _Float16* y1 = y0 + (size_t)N0 * 32;        // [N1,64]  s2
    _Float16* y2 = y1 + (size_t)N1 * 64;        // [N2,128] s4
    _Float16* y3 = y2 + (size_t)N2 * 128;       // [N1,64]  d2
    _Float16* y4 = y3 + (size_t)N1 * 64;        // [N0,64]  d1
    int* mapT = (int*)(y4 + (size_t)N0 * 64);   // [Nmax,32] transposed map
    const _Float16* zrh = (const _Float16*)zrow;

    (void)hipMemsetAsync(sums, 0, (704 + 128) * sizeof(float), stream);

    // weight transposes (tiny)
    wtrans<16, 32><<<(27 * 4 * 32 + 255) / 256, 256, 0, stream>>>(W0, Wt0);
    wtrans_h<32, 64><<<(27 * 4 * 64 + 255) / 256, 256, 0, stream>>>(W1, Wh1);
    wtrans_h<64, 128><<<(27 * 8 * 128 + 255) / 256, 256, 0, stream>>>(W2, Wh2);
    wtrans_h<128, 64><<<(27 * 16 * 64 + 255) / 256, 256, 0, stream>>>(W2t, Wh2t);
    wtrans_h<128, 64><<<(27 * 16 * 64 + 255) / 256, 256, 0, stream>>>(W1t, Wh1t);

    // block0: feats[N0,16] fp32 -> y0[N0,32] half
    sconv0<<<(N0 + 7) / 8, 256, 0, stream>>>(feats, Wt0, map0, N0, y0, zrow);
    bn_reduce_h<32><<<256, 256, 0, stream>>>(y0, N0, sums0);
    bn_apply_h<32><<<512, 256, 0, stream>>>(y0, N0, sums0, g0, b0);

    // block1 (SPARSE map): one wave per row
    map_transpose<<<(N1 + 255) / 256, 256, 0, stream>>>(map1, N1, mapT);
    sconv_r1<32, 32, 64><<<(N1 + 3) / 4, 256, 0, stream>>>(
        y0, nullptr, Wh1, mapT, N1, y1);
    bn_reduce_h<64><<<256, 256, 0, stream>>>(y1, N1, sums1);
    bn_apply_h<64><<<512, 256, 0, stream>>>(y1, N1, sums1, g1, b1);

    // block2 (DENSE map ~30%): R=8 rows/wave, inverted loops
    sconv_big_h<64, 64, 128, 8><<<(N2 + 31) / 32, 256, 0, stream>>>(
        y1, nullptr, Wh2, map2, N2, y2);
    bn_reduce_h<128><<<256, 256, 0, stream>>>(y2, N2, sums2);
    bn_apply_h<128><<<512, 256, 0, stream>>>(y2, N2, sums2, g2, b2);

    // block2_tr (MID map ~12.5%): R=4 rows/wave, inverted loops
    sconv_big_h<128, 128, 64, 4><<<(N1 + 15) / 16, 256, 0, stream>>>(
        y2, nullptr, Wh2t, map2t, N1, y3);
    bn_reduce_h<64><<<256, 256, 0, stream>>>(y3, N1, sums3);
    bn_apply_h<64><<<512, 256, 0, stream>>>(y3, N1, sums3, g2t, b2t);

    // block1_tr (SPARSE map): R=8 rows/wave, inverted loops.
    // Was sconv_r1 (1 row/wave): that reloaded the full 16KB W k-slice per
    // row per active k (~11 GB of L2 traffic). Union-of-k over 8 consecutive
    // rows only saturates the z-parity dim (~6.75 vs 3.4 candidates), so W
    // traffic per row drops ~4x; also drops the map1t map_transpose pass.
    sconv_big_h<128, 64, 64, 8><<<(N0 + 31) / 32, 256, 0, stream>>>(
        y3, y1, Wh1t, map1t, N0, y4);
    bn_reduce_h<64><<<256, 256, 0, stream>>>(y4, N0, sums4);
    bn_apply_h<64><<<512, 256, 0, stream>>>(y4, N0, sums4, g1t, b1t);

    // block0_tr: concat(d1,s1)[N0,96] -> out[N0,2] fp32
    sconv0t<<<(N0 + 7) / 8, 256, 0, stream>>>(y4, y0, W0t, map0t, N0,
                                              (float*)d_out, zrh);
}

// Round 2
// 1034.577 us; speedup vs baseline: 1.1017x; 1.0159x over previous
//
#include <hip/hip_runtime.h>
#include <cstddef>
#include <cstdint>

#define BN_EPS 1e-5f

typedef float f4 __attribute__((ext_vector_type(4)));
typedef _Float16 h2 __attribute__((ext_vector_type(2)));
typedef _Float16 h8 __attribute__((ext_vector_type(8)));

#if defined(__has_builtin)
#if __has_builtin(__builtin_amdgcn_fdot2)
#define DOT2(a, b, c) __builtin_amdgcn_fdot2((a), (b), (c), false)
#endif
#endif
#ifndef DOT2
#define DOT2(a, b, c) fmaf((float)(a)[1], (float)(b)[1], fmaf((float)(a)[0], (float)(b)[0], (c)))
#endif

// ---------------------------------------------------------------------------
// fp32 weight transpose (sconv0 only): W[27][CIN][COUT] -> Wt[k][ci/4][co][4]
// ---------------------------------------------------------------------------
template<int CIN, int COUT>
__global__ __launch_bounds__(256)
void wtrans(const float* __restrict__ W, float* __restrict__ Wt)
{
    const int t = blockIdx.x * 256 + threadIdx.x;
    constexpr int TOTAL = 27 * (CIN / 4) * COUT;
    if (t >= TOTAL) return;
    const int co = t % COUT;
    const int rest = t / COUT;
    const int c4 = rest % (CIN / 4);
    const int k  = rest / (CIN / 4);
    f4 v;
    #pragma unroll
    for (int u = 0; u < 4; ++u)
        v[u] = W[((size_t)k * CIN + c4 * 4 + u) * COUT + co];
    *(f4*)(Wt + (size_t)t * 4) = v;
}

// ---------------------------------------------------------------------------
// f16 weight transpose: W[27][CIN][COUT] -> Wh[k][ci/8][co][8]
// ---------------------------------------------------------------------------
template<int CIN, int COUT>
__global__ __launch_bounds__(256)
void wtrans_h(const float* __restrict__ W, _Float16* __restrict__ Wh)
{
    const int t = blockIdx.x * 256 + threadIdx.x;
    constexpr int TOTAL = 27 * (CIN / 8) * COUT;
    if (t >= TOTAL) return;
    const int co = t % COUT;
    const int rest = t / COUT;
    const int t8 = rest % (CIN / 8);
    const int k  = rest / (CIN / 8);
    h8 v;
    #pragma unroll
    for (int u = 0; u < 8; ++u)
        v[u] = (_Float16)W[((size_t)k * CIN + t8 * 8 + u) * COUT + co];
    *(h8*)(Wh + (size_t)t * 8) = v;
}

// ---------------------------------------------------------------------------
// Map transpose: map[27][Nout] -> mapT[Nout][32] (k-major per row, -1 pad).
// ---------------------------------------------------------------------------
__global__ __launch_bounds__(256)
void map_transpose(const int* __restrict__ map, int Nout,
                   int* __restrict__ mapT)
{
    __shared__ int s[256][28];
    const int tid  = threadIdx.x;
    const int base = blockIdx.x * 256;
    const int j    = base + tid;
    for (int k = 0; k < 27; ++k)
        s[tid][k] = (j < Nout) ? map[(size_t)k * Nout + j] : -1;
    __syncthreads();
    for (int i = tid; i < 256 * 32; i += 256) {
        const int r = i >> 5, c = i & 31;
        if (base + r < Nout)
            mapT[(size_t)(base + r) * 32 + c] = (c < 27) ? s[r][c] : -1;
    }
}

// ---------------------------------------------------------------------------
// R=1 f16 sparse conv (SPARSE maps): one wave = one row.
// ---------------------------------------------------------------------------
template<int CIN, int CINA, int COUT>
__global__ __launch_bounds__(256)
void sconv_r1(const _Float16* __restrict__ xA, const _Float16* __restrict__ xB,
              const _Float16* __restrict__ Wh, const int* __restrict__ mapT,
              int Nout, _Float16* __restrict__ out)
{
    constexpr int CINB = CIN - CINA;
    constexpr int CPL  = COUT / 64;
    constexpr int NT   = CIN / 8;
    const int lane = threadIdx.x & 63;
    const int j    = blockIdx.x * 4 + (threadIdx.x >> 6);

    int mk = -1;
    if (j < Nout && lane < 32) mk = mapT[(size_t)j * 32 + lane];
    unsigned long long act = __ballot(mk >= 0);   // bits 0..26 only

    float acc[CPL];
    #pragma unroll
    for (int c = 0; c < CPL; ++c) acc[c] = 0.f;

    while (act) {
        const int k = (int)__builtin_ctzll(act);
        act &= act - 1;
        const int m = __builtin_amdgcn_readlane(mk, k);   // uniform SGPR

        const _Float16* pA = xA + (size_t)m * CINA;
        const _Float16* pB = nullptr;
        if constexpr (CINB > 0) pB = xB + (size_t)m * CINB;

        const _Float16* Wk = Wh + (size_t)k * NT * COUT * 8;

        #pragma unroll
        for (int t = 0; t < NT; ++t) {
            const int ci = t * 8;
            h8 wv[CPL];
            #pragma unroll
            for (int c = 0; c < CPL; ++c)
                wv[c] = *(const h8*)(Wk + ((size_t)t * COUT + c * 64 + lane) * 8);
            const _Float16* p;
            if constexpr (CINB > 0)
                p = (ci < CINA) ? (pA + ci) : (pB + (ci - CINA));
            else
                p = pA + ci;
            const h8 xv = *(const h8*)p;
            const h2* xp = (const h2*)&xv;
            #pragma unroll
            for (int q = 0; q < 4; ++q) {
                #pragma unroll
                for (int c = 0; c < CPL; ++c) {
                    const h2* wp = (const h2*)&wv[c];
                    acc[c] = DOT2(xp[q], wp[q], acc[c]);
                }
            }
        }
    }

    if (j < Nout) {
        #pragma unroll
        for (int c = 0; c < CPL; ++c)
            out[(size_t)j * COUT + c * 64 + lane] = (_Float16)acc[c];
    }
}

// ---------------------------------------------------------------------------
// R-rows/wave f16 sparse conv (DENSE/MID/SPARSE maps), loop inversion:
// per active k (union over R rows), the ENTIRE W k-slice is preloaded into
// registers (NT*CPL h8), then rows loop OUTSIDE the tile loop: ONE uniform
// guard per row, batched x s_loads inside the guard, then the dot2 block.
// W traffic per row drops ~R/union_blowup vs the r1 kernel. For parity-gated
// transpose maps the union saturates after ~4 rows (z dim only), so large R
// amortizes the same W loads over ~R rows nearly linearly.
// ---------------------------------------------------------------------------
template<int CIN, int CINA, int COUT, int R>
__global__ __launch_bounds__(256)
void sconv_big_h(const _Float16* __restrict__ xA, const _Float16* __restrict__ xB,
                 const _Float16* __restrict__ Wh, const int* __restrict__ map,
                 int Nout, _Float16* __restrict__ out)
{
    constexpr int CINB = CIN - CINA;
    constexpr int CPL  = COUT / 64;
    constexpr int NT   = CIN / 8;
    const int lane = threadIdx.x & 63;
    const int wave = threadIdx.x >> 6;
    const int row0 = (blockIdx.x * 4 + wave) * R;

    int mk[R];
    bool anyv = false;
    #pragma unroll
    for (int r = 0; r < R; ++r) {
        const int j = row0 + r;
        mk[r] = (lane < 27 && j < Nout) ? map[(size_t)lane * Nout + j] : -1;
        anyv |= (mk[r] >= 0);
    }
    unsigned long long act = __ballot(anyv);

    float acc[R][CPL];
    #pragma unroll
    for (int r = 0; r < R; ++r)
        #pragma unroll
        for (int c = 0; c < CPL; ++c) acc[r][c] = 0.f;

    while (act) {
        const int k = (int)__builtin_ctzll(act);
        act &= act - 1;

        // ---- preload the full W k-slice into registers ----
        const _Float16* Wk = Wh + (size_t)k * NT * COUT * 8;
        h8 wv[NT][CPL];
        #pragma unroll
        for (int t = 0; t < NT; ++t)
            #pragma unroll
            for (int c = 0; c < CPL; ++c)
                wv[t][c] = *(const h8*)(Wk + ((size_t)t * COUT + c * 64 + lane) * 8);

        // ---- per row: one guard, batched s_loads, dot2 block ----
        #pragma unroll
        for (int r = 0; r < R; ++r) {
            const int m = __builtin_amdgcn_readlane(mk[r], k);  // uniform SGPR
            if (m >= 0) {
                h8 xv[NT];
                #pragma unroll
                for (int t = 0; t < NT; ++t) {
                    const int ci = t * 8;
                    const _Float16* p;
                    if constexpr (CINB > 0)
                        p = (ci < CINA) ? (xA + (size_t)m * CINA + ci)
                                        : (xB + (size_t)m * CINB + (ci - CINA));
                    else
                        p = xA + (size_t)m * CINA + ci;
                    xv[t] = *(const h8*)p;
                }
                #pragma unroll
                for (int t = 0; t < NT; ++t) {
                    const h2* xp = (const h2*)&xv[t];
                    #pragma unroll
                    for (int q = 0; q < 4; ++q) {
                        #pragma unroll
                        for (int c = 0; c < CPL; ++c) {
                            const h2* wp = (const h2*)&wv[t][c];
                            acc[r][c] = DOT2(xp[q], wp[q], acc[r][c]);
                        }
                    }
                }
            }
        }
    }

    #pragma unroll
    for (int r = 0; r < R; ++r) {
        const int j = row0 + r;
        if (j < Nout) {
            #pragma unroll
            for (int c = 0; c < CPL; ++c)
                out[(size_t)j * COUT + c * 64 + lane] = (_Float16)acc[r][c];
        }
    }
}

// ---------------------------------------------------------------------------
// conv0: CIN=16 (fp32 feats), COUT=32 -> half out. 2 rows/wave, ctz-union.
// ---------------------------------------------------------------------------
__global__ __launch_bounds__(256)
void sconv0(const float* __restrict__ x, const float* __restrict__ Wt,
            const int* __restrict__ map, int N, _Float16* __restrict__ out,
            const float* __restrict__ zrow)
{
    const int tid  = threadIdx.x;
    const int lane = tid & 63;
    const int l32  = tid & 31;
    const int co   = l32;
    const int j    = blockIdx.x * 8 + (tid >> 5);

    int mk = (l32 < 27 && j < N) ? map[(size_t)l32 * N + j] : -1;
    const unsigned long long bal = __ballot(mk >= 0);
    unsigned int act = (unsigned int)((bal | (bal >> 32)) & 0x7FFFFFFu);

    float a0 = 0.f, a1 = 0.f, a2 = 0.f, a3 = 0.f;
    while (act) {
        const int k = (int)__builtin_ctz(act);
        act &= act - 1;
        const int m = __shfl(mk, (lane & 32) + k);
        const float* xr = (m >= 0) ? (x + (size_t)m * 16) : zrow;
        const float* wk = Wt + (size_t)k * 16 * 32;
        f4 w0 = *(const f4*)(wk + (0 * 32 + co) * 4);
        f4 w1 = *(const f4*)(wk + (1 * 32 + co) * 4);
        f4 w2 = *(const f4*)(wk + (2 * 32 + co) * 4);
        f4 w3 = *(const f4*)(wk + (3 * 32 + co) * 4);
        f4 x0 = *(const f4*)(xr);
        f4 x1 = *(const f4*)(xr + 4);
        f4 x2 = *(const f4*)(xr + 8);
        f4 x3 = *(const f4*)(xr + 12);
        #pragma unroll
        for (int u = 0; u < 4; ++u) {
            a0 = fmaf(x0[u], w0[u], a0);
            a1 = fmaf(x1[u], w1[u], a1);
            a2 = fmaf(x2[u], w2[u], a2);
            a3 = fmaf(x3[u], w3[u], a3);
        }
    }
    if (j < N) out[(size_t)j * 32 + co] = (_Float16)((a0 + a1) + (a2 + a3));
}

// ---------------------------------------------------------------------------
// conv0t: concat(d1[*,64]h, s1[*,32]h) -> out[N0,2] fp32. ctz-union loop.
// ---------------------------------------------------------------------------
__global__ __launch_bounds__(256)
void sconv0t(const _Float16* __restrict__ d1, const _Float16* __restrict__ s1,
             const float* __restrict__ W /*[27,96,2]*/,
             const int* __restrict__ map, int N, float* __restrict__ out,
             const _Float16* __restrict__ zrh)
{
    const int tid  = threadIdx.x;
    const int lane = tid & 63;
    const int l32  = tid & 31;
    const int j    = blockIdx.x * 8 + (tid >> 5);

    int mk = (l32 < 27 && j < N) ? map[(size_t)l32 * N + j] : -1;
    const unsigned long long bal = __ballot(mk >= 0);
    unsigned int act = (unsigned int)((bal | (bal >> 32)) & 0x7FFFFFFu);

    float a0 = 0.f, a1 = 0.f;
    while (act) {
        const int k = (int)__builtin_ctz(act);
        act &= act - 1;
        const int m = __shfl(mk, (lane & 32) + k);
        const _Float16* p1 = (m >= 0) ? (d1 + (size_t)m * 64) : zrh;
        const _Float16* p2 = (m >= 0) ? (s1 + (size_t)m * 32) : zrh;
        const float* w = W + (size_t)k * 96 * 2;
        const float x0 = (float)p1[l32];
        const float x1 = (float)p1[l32 + 32];
        const float x2 = (float)p2[l32];
        a0 = fmaf(x0, w[l32 * 2 + 0], a0);
        a1 = fmaf(x0, w[l32 * 2 + 1], a1);
        a0 = fmaf(x1, w[(l32 + 32) * 2 + 0], a0);
        a1 = fmaf(x1, w[(l32 + 32) * 2 + 1], a1);
        a0 = fmaf(x2, w[(l32 + 64) * 2 + 0], a0);
        a1 = fmaf(x2, w[(l32 + 64) * 2 + 1], a1);
    }
    #pragma unroll
    for (int off = 1; off < 32; off <<= 1) {
        a0 += __shfl_xor(a0, off, 32);
        a1 += __shfl_xor(a1, off, 32);
    }
    if (l32 == 0 && j < N) {
        out[(size_t)j * 2 + 0] = a0;
        out[(size_t)j * 2 + 1] = a1;
    }
}

// ---------------------------------------------------------------------------
// BN pass 1 on half tensors
// ---------------------------------------------------------------------------
template<int C>
__global__ __launch_bounds__(256)
void bn_reduce_h(const _Float16* __restrict__ x, int N,
                 float* __restrict__ sums)
{
    constexpr int RG = 256 / C;
    const int tid = threadIdx.x;
    const int c   = tid % C;
    const int rg  = tid / C;
    float s = 0.f, s2 = 0.f;
    for (int j = blockIdx.x * RG + rg; j < N; j += gridDim.x * RG) {
        const float v = (float)x[(size_t)j * C + c];
        s += v;
        s2 += v * v;
    }
    __shared__ float sh[2 * 256];
    sh[tid] = s;
    sh[256 + tid] = s2;
    __syncthreads();
    for (int stride = 128; stride >= C; stride >>= 1) {
        if (tid < stride) {
            sh[tid] += sh[tid + stride];
            sh[256 + tid] += sh[256 + tid + stride];
        }
        __syncthreads();
    }
    if (tid < C) {
        atomicAdd(&sums[c], sh[tid]);
        atomicAdd(&sums[C + c], sh[256 + tid]);
    }
}

// ---------------------------------------------------------------------------
// BN pass 2 on half tensors
// ---------------------------------------------------------------------------
template<int C>
__global__ __launch_bounds__(256)
void bn_apply_h(_Float16* __restrict__ x, int N,
                const float* __restrict__ sums,
                const float* __restrict__ g, const float* __restrict__ b)
{
    const int tid = blockIdx.x * blockDim.x + threadIdx.x;
    const int c = tid % C;
    const float invN = 1.0f / (float)N;
    const float mean = sums[c] * invN;
    float var = sums[C + c] * invN - mean * mean;
    var = fmaxf(var, 0.f);
    const float sc = g[c] * rsqrtf(var + BN_EPS);
    const float sh = b[c] - mean * sc;
    const int rows_stride = (gridDim.x * blockDim.x) / C;
    for (int j = tid / C; j < N; j += rows_stride) {
        const size_t i = (size_t)j * C + c;
        const float v = fmaf((float)x[i], sc, sh);
        x[i] = (_Float16)(v > 0.f ? v : 0.f);
    }
}

// ---------------------------------------------------------------------------
extern "C" void kernel_launch(void* const* d_in, const int* in_sizes, int n_in,
                              void* d_out, int out_size, void* d_ws, size_t ws_size,
                              hipStream_t stream)
{
    const float* feats = (const float*)d_in[0];
    const float* W0  = (const float*)d_in[1];
    const float* g0  = (const float*)d_in[2];
    const float* b0  = (const float*)d_in[3];
    const float* W1  = (const float*)d_in[4];
    const float* g1  = (const float*)d_in[5];
    const float* b1  = (const float*)d_in[6];
    const float* W2  = (const float*)d_in[7];
    const float* g2  = (const float*)d_in[8];
    const float* b2  = (const float*)d_in[9];
    const float* W2t = (const float*)d_in[10];
    const float* g2t = (const float*)d_in[11];
    const float* b2t = (const float*)d_in[12];
    const float* W1t = (const float*)d_in[13];
    const float* g1t = (const float*)d_in[14];
    const float* b1t = (const float*)d_in[15];
    const float* W0t = (const float*)d_in[16];
    const int* map0  = (const int*)d_in[17];
    const int* map1  = (const int*)d_in[18];
    const int* map2  = (const int*)d_in[19];
    const int* map2t = (const int*)d_in[20];
    const int* map1t = (const int*)d_in[21];
    const int* map0t = (const int*)d_in[22];

    const int N0 = in_sizes[0] / 16;
    const int N1 = in_sizes[18] / 27;
    const int N2 = in_sizes[19] / 27;

    float* ws = (float*)d_ws;
    float* sums  = ws;          // 704 floats of BN accumulators
    float* sums0 = sums;        // 2*32
    float* sums1 = sums + 64;   // 2*64
    float* sums2 = sums + 192;  // 2*128
    float* sums3 = sums + 448;  // 2*64
    float* sums4 = sums + 576;  // 2*64
    float* zrow  = sums + 704;  // 128 zeroed floats (fp32 & f16 zero rows)
    float* Wt0   = zrow + 128;  // 27*16*32 fp32
    _Float16* hb = (_Float16*)(Wt0 + 27 * 16 * 32);
    _Float16* Wh1  = hb;                        // 27*32*64
    _Float16* Wh2  = Wh1 + 27 * 32 * 64;        // 27*64*128
    _Float16* Wh2t = Wh2 + 27 * 64 * 128;       // 27*128*64
    _Float16* Wh1t = Wh2t + 27 * 128 * 64;      // 27*128*64
    _Float16* y0 = Wh1t + 27 * 128 * 64;        // [N0,32]  s1
    _Float16* y1 = y0 + (size_t)N0 * 32;        // [N1,64]  s2
    _Float16* y2 = y1 + (size_t)N1 * 64;        // [N2,128] s4
    _Float16* y3 = y2 + (size_t)N2 * 128;       // [N1,64]  d2
    _Float16* y4 = y3 + (size_t)N1 * 64;        // [N0,64]  d1
    int* mapT = (int*)(y4 + (size_t)N0 * 64);   // [Nmax,32] transposed map
    const _Float16* zrh = (const _Float16*)zrow;

    (void)hipMemsetAsync(sums, 0, (704 + 128) * sizeof(float), stream);

    // weight transposes (tiny)
    wtrans<16, 32><<<(27 * 4 * 32 + 255) / 256, 256, 0, stream>>>(W0, Wt0);
    wtrans_h<32, 64><<<(27 * 4 * 64 + 255) / 256, 256, 0, stream>>>(W1, Wh1);
    wtrans_h<64, 128><<<(27 * 8 * 128 + 255) / 256, 256, 0, stream>>>(W2, Wh2);
    wtrans_h<128, 64><<<(27 * 16 * 64 + 255) / 256, 256, 0, stream>>>(W2t, Wh2t);
    wtrans_h<128, 64><<<(27 * 16 * 64 + 255) / 256, 256, 0, stream>>>(W1t, Wh1t);

    // block0: feats[N0,16] fp32 -> y0[N0,32] half
    sconv0<<<(N0 + 7) / 8, 256, 0, stream>>>(feats, Wt0, map0, N0, y0, zrow);
    bn_reduce_h<32><<<256, 256, 0, stream>>>(y0, N0, sums0);
    bn_apply_h<32><<<512, 256, 0, stream>>>(y0, N0, sums0, g0, b0);

    // block1 (SPARSE map): one wave per row
    map_transpose<<<(N1 + 255) / 256, 256, 0, stream>>>(map1, N1, mapT);
    sconv_r1<32, 32, 64><<<(N1 + 3) / 4, 256, 0, stream>>>(
        y0, nullptr, Wh1, mapT, N1, y1);
    bn_reduce_h<64><<<256, 256, 0, stream>>>(y1, N1, sums1);
    bn_apply_h<64><<<512, 256, 0, stream>>>(y1, N1, sums1, g1, b1);

    // block2 (DENSE map ~30%): R=16 rows/wave -- union of active k is <=27
    // and near-saturated already at R=8, so doubling R roughly halves the
    // per-row W k-slice register-reload (L1) traffic.
    sconv_big_h<64, 64, 128, 16><<<(N2 + 63) / 64, 256, 0, stream>>>(
        y1, nullptr, Wh2, map2, N2, y2);
    bn_reduce_h<128><<<256, 256, 0, stream>>>(y2, N2, sums2);
    bn_apply_h<128><<<512, 256, 0, stream>>>(y2, N2, sums2, g2, b2);

    // block2_tr (MID map, parity-gated): R=16 rows/wave. The k-union
    // saturates at ~6.75 (only z-parity varies across consecutive rows),
    // so R=4->16 cuts W traffic/row ~4x at the same union cost.
    sconv_big_h<128, 128, 64, 16><<<(N1 + 63) / 64, 256, 0, stream>>>(
        y2, nullptr, Wh2t, map2t, N1, y3);
    bn_reduce_h<64><<<256, 256, 0, stream>>>(y3, N1, sums3);
    bn_apply_h<64><<<512, 256, 0, stream>>>(y3, N1, sums3, g2t, b2t);

    // block1_tr (parity-gated, z-saturated union): R=16 rows/wave.
    sconv_big_h<128, 64, 64, 16><<<(N0 + 63) / 64, 256, 0, stream>>>(
        y3, y1, Wh1t, map1t, N0, y4);
    bn_reduce_h<64><<<256, 256, 0, stream>>>(y4, N0, sums4);
    bn_apply_h<64><<<512, 256, 0, stream>>>(y4, N0, sums4, g1t, b1t);

    // block0_tr: concat(d1,s1)[N0,96] -> out[N0,2] fp32
    sconv0t<<<(N0 + 7) / 8, 256, 0, stream>>>(y4, y0, W0t, map0t, N0,
                                              (float*)d_out, zrh);
}

// Round 3
// 973.613 us; speedup vs baseline: 1.1707x; 1.0626x over previous
//
#include <hip/hip_runtime.h>
#include <cstddef>
#include <cstdint>

#define BN_EPS 1e-5f

typedef float f4 __attribute__((ext_vector_type(4)));
typedef float f32x4 __attribute__((ext_vector_type(4)));
typedef _Float16 h2 __attribute__((ext_vector_type(2)));
typedef _Float16 h8 __attribute__((ext_vector_type(8)));

#if defined(__has_builtin)
#if __has_builtin(__builtin_amdgcn_fdot2)
#define DOT2(a, b, c) __builtin_amdgcn_fdot2((a), (b), (c), false)
#endif
#endif
#ifndef DOT2
#define DOT2(a, b, c) fmaf((float)(a)[1], (float)(b)[1], fmaf((float)(a)[0], (float)(b)[0], (c)))
#endif

// ---------------------------------------------------------------------------
// fp32 weight transpose (sconv0 only): W[27][CIN][COUT] -> Wt[k][ci/4][co][4]
// ---------------------------------------------------------------------------
template<int CIN, int COUT>
__global__ __launch_bounds__(256)
void wtrans(const float* __restrict__ W, float* __restrict__ Wt)
{
    const int t = blockIdx.x * 256 + threadIdx.x;
    constexpr int TOTAL = 27 * (CIN / 4) * COUT;
    if (t >= TOTAL) return;
    const int co = t % COUT;
    const int rest = t / COUT;
    const int c4 = rest % (CIN / 4);
    const int k  = rest / (CIN / 4);
    f4 v;
    #pragma unroll
    for (int u = 0; u < 4; ++u)
        v[u] = W[((size_t)k * CIN + c4 * 4 + u) * COUT + co];
    *(f4*)(Wt + (size_t)t * 4) = v;
}

// ---------------------------------------------------------------------------
// f16 weight transpose (sconv_r1): W[27][CIN][COUT] -> Wh[k][ci/8][co][8]
// ---------------------------------------------------------------------------
template<int CIN, int COUT>
__global__ __launch_bounds__(256)
void wtrans_h(const float* __restrict__ W, _Float16* __restrict__ Wh)
{
    const int t = blockIdx.x * 256 + threadIdx.x;
    constexpr int TOTAL = 27 * (CIN / 8) * COUT;
    if (t >= TOTAL) return;
    const int co = t % COUT;
    const int rest = t / COUT;
    const int t8 = rest % (CIN / 8);
    const int k  = rest / (CIN / 8);
    h8 v;
    #pragma unroll
    for (int u = 0; u < 8; ++u)
        v[u] = (_Float16)W[((size_t)k * CIN + t8 * 8 + u) * COUT + co];
    *(h8*)(Wh + (size_t)t * 8) = v;
}

// ---------------------------------------------------------------------------
// MFMA weight transform: W[27][CIN][COUT] fp32 -> B-fragment layout f16:
// Wm[((k*NT + t)*NC + ct)*64 + lane][8], where the h8 for `lane` holds
// B[kk][co] with kk = t*32 + (lane>>4)*8 + u, co = ct*16 + (lane&15).
// Matches the mfma_f32_16x16x32_f16 B operand slot layout.
// ---------------------------------------------------------------------------
template<int CIN, int COUT>
__global__ __launch_bounds__(256)
void wtrans_mf(const float* __restrict__ W, _Float16* __restrict__ Wm)
{
    constexpr int NT = CIN / 32;
    constexpr int NC = COUT / 16;
    const int t = blockIdx.x * 256 + threadIdx.x;
    constexpr int TOTAL = 27 * NT * NC * 64;
    if (t >= TOTAL) return;
    const int lane = t & 63;
    int rest = t >> 6;
    const int ct = rest % NC; rest /= NC;
    const int tt = rest % NT;
    const int k  = rest / NT;
    const int cin0 = tt * 32 + (lane >> 4) * 8;
    const int co   = ct * 16 + (lane & 15);
    h8 v;
    #pragma unroll
    for (int u = 0; u < 8; ++u)
        v[u] = (_Float16)W[((size_t)k * CIN + cin0 + u) * COUT + co];
    *(h8*)(Wm + (size_t)t * 8) = v;
}

// ---------------------------------------------------------------------------
// Map transpose: map[27][Nout] -> mapT[Nout][32] (k-major per row, -1 pad).
// ---------------------------------------------------------------------------
__global__ __launch_bounds__(256)
void map_transpose(const int* __restrict__ map, int Nout,
                   int* __restrict__ mapT)
{
    __shared__ int s[256][28];
    const int tid  = threadIdx.x;
    const int base = blockIdx.x * 256;
    const int j    = base + tid;
    for (int k = 0; k < 27; ++k)
        s[tid][k] = (j < Nout) ? map[(size_t)k * Nout + j] : -1;
    __syncthreads();
    for (int i = tid; i < 256 * 32; i += 256) {
        const int r = i >> 5, c = i & 31;
        if (base + r < Nout)
            mapT[(size_t)(base + r) * 32 + c] = (c < 27) ? s[r][c] : -1;
    }
}

// ---------------------------------------------------------------------------
// R=1 f16 sparse conv (SPARSE maps): one wave = one row.
// ---------------------------------------------------------------------------
template<int CIN, int CINA, int COUT>
__global__ __launch_bounds__(256)
void sconv_r1(const _Float16* __restrict__ xA, const _Float16* __restrict__ xB,
              const _Float16* __restrict__ Wh, const int* __restrict__ mapT,
              int Nout, _Float16* __restrict__ out)
{
    constexpr int CINB = CIN - CINA;
    constexpr int CPL  = COUT / 64;
    constexpr int NT   = CIN / 8;
    const int lane = threadIdx.x & 63;
    const int j    = blockIdx.x * 4 + (threadIdx.x >> 6);

    int mk = -1;
    if (j < Nout && lane < 32) mk = mapT[(size_t)j * 32 + lane];
    unsigned long long act = __ballot(mk >= 0);   // bits 0..26 only

    float acc[CPL];
    #pragma unroll
    for (int c = 0; c < CPL; ++c) acc[c] = 0.f;

    while (act) {
        const int k = (int)__builtin_ctzll(act);
        act &= act - 1;
        const int m = __builtin_amdgcn_readlane(mk, k);   // uniform SGPR

        const _Float16* pA = xA + (size_t)m * CINA;
        const _Float16* pB = nullptr;
        if constexpr (CINB > 0) pB = xB + (size_t)m * CINB;

        const _Float16* Wk = Wh + (size_t)k * NT * COUT * 8;

        #pragma unroll
        for (int t = 0; t < NT; ++t) {
            const int ci = t * 8;
            h8 wv[CPL];
            #pragma unroll
            for (int c = 0; c < CPL; ++c)
                wv[c] = *(const h8*)(Wk + ((size_t)t * COUT + c * 64 + lane) * 8);
            const _Float16* p;
            if constexpr (CINB > 0)
                p = (ci < CINA) ? (pA + ci) : (pB + (ci - CINA));
            else
                p = pA + ci;
            const h8 xv = *(const h8*)p;
            const h2* xp = (const h2*)&xv;
            #pragma unroll
            for (int q = 0; q < 4; ++q) {
                #pragma unroll
                for (int c = 0; c < CPL; ++c) {
                    const h2* wp = (const h2*)&wv[c];
                    acc[c] = DOT2(xp[q], wp[q], acc[c]);
                }
            }
        }
    }

    if (j < Nout) {
        #pragma unroll
        for (int c = 0; c < CPL; ++c)
            out[(size_t)j * COUT + c * 64 + lane] = (_Float16)acc[c];
    }
}

// ---------------------------------------------------------------------------
// MFMA sparse conv: one wave = 16 output rows. Per active k (union over the
// 16 rows), the k-step is a dense [16 x CIN] x [CIN x COUT] GEMM done with
// mfma_f32_16x16x32_f16. Rows with no neighbor at this k gather from a zero
// row (contribute 0). A and B use the SAME slot->cin mapping, so the result
// is invariant to the HW k-permutation; D layout is the HW-verified
// col=lane&15, row=(lane>>4)*4+reg.
// ---------------------------------------------------------------------------
template<int CIN, int CINA, int COUT>
__global__ __launch_bounds__(256)
void sconv_mf(const _Float16* __restrict__ xA, const _Float16* __restrict__ xB,
              const _Float16* __restrict__ Wm, const int* __restrict__ map,
              int Nout, _Float16* __restrict__ out,
              const _Float16* __restrict__ zrh)
{
    constexpr int CINB = CIN - CINA;
    constexpr int NT = CIN / 32;    // K chunks of 32
    constexpr int NC = COUT / 16;   // cout tiles of 16
    static_assert(CINA % 32 == 0, "CINA must be a multiple of 32");
    const int lane = threadIdx.x & 63;
    const int wave = threadIdx.x >> 6;
    const int row0 = (blockIdx.x * 4 + wave) * 16;

    // union-of-k mask: lane k holds the 16 map entries of its k
    int mk[16];
    bool anyv = false;
    #pragma unroll
    for (int r = 0; r < 16; ++r) {
        const int j = row0 + r;
        mk[r] = (lane < 27 && j < Nout) ? map[(size_t)lane * Nout + j] : -1;
        anyv |= (mk[r] >= 0);
    }
    unsigned long long act = __ballot(anyv);

    f32x4 acc[NC];
    #pragma unroll
    for (int c = 0; c < NC; ++c) acc[c] = (f32x4){0.f, 0.f, 0.f, 0.f};

    const int rrow = lane & 15;   // A row this lane gathers / D col
    const int kseg = lane >> 4;   // k segment
    const int jj   = row0 + rrow;
    const int jc   = (jj < Nout) ? jj : (Nout - 1);   // clamped map index

    while (act) {
        const int k = (int)__builtin_ctzll(act);
        act &= act - 1;

        // per-lane neighbor row for this k (L1-hot line, 16 consecutive ints)
        int m = map[(size_t)k * Nout + jc];
        if (jj >= Nout) m = -1;

        const _Float16* Wk = Wm + ((size_t)k * NT * NC * 64 + lane) * 8;

        #pragma unroll
        for (int t = 0; t < NT; ++t) {
            const int cin0 = t * 32 + kseg * 8;
            const _Float16* pa;
            if (m >= 0) {
                if (CINB > 0 && t * 32 >= CINA)
                    pa = xB + (size_t)m * CINB + (cin0 - CINA);
                else
                    pa = xA + (size_t)m * CINA + cin0;
            } else {
                pa = zrh;
            }
            const h8 a = *(const h8*)pa;
            #pragma unroll
            for (int c = 0; c < NC; ++c) {
                const h8 b = *(const h8*)(Wk + (size_t)(t * NC + c) * 64 * 8);
                acc[c] = __builtin_amdgcn_mfma_f32_16x16x32_f16(a, b, acc[c], 0, 0, 0);
            }
        }
    }

    // D: lane (kseg,rrow), reg r -> row = kseg*4 + r, col = rrow
    #pragma unroll
    for (int c = 0; c < NC; ++c) {
        #pragma unroll
        for (int r = 0; r < 4; ++r) {
            const int j = row0 + kseg * 4 + r;
            if (j < Nout)
                out[(size_t)j * COUT + c * 16 + rrow] = (_Float16)acc[c][r];
        }
    }
}

// ---------------------------------------------------------------------------
// conv0: CIN=16 (fp32 feats), COUT=32 -> half out. 2 rows/wave, ctz-union.
// ---------------------------------------------------------------------------
__global__ __launch_bounds__(256)
void sconv0(const float* __restrict__ x, const float* __restrict__ Wt,
            const int* __restrict__ map, int N, _Float16* __restrict__ out,
            const float* __restrict__ zrow)
{
    const int tid  = threadIdx.x;
    const int lane = tid & 63;
    const int l32  = tid & 31;
    const int co   = l32;
    const int j    = blockIdx.x * 8 + (tid >> 5);

    int mk = (l32 < 27 && j < N) ? map[(size_t)l32 * N + j] : -1;
    const unsigned long long bal = __ballot(mk >= 0);
    unsigned int act = (unsigned int)((bal | (bal >> 32)) & 0x7FFFFFFu);

    float a0 = 0.f, a1 = 0.f, a2 = 0.f, a3 = 0.f;
    while (act) {
        const int k = (int)__builtin_ctz(act);
        act &= act - 1;
        const int m = __shfl(mk, (lane & 32) + k);
        const float* xr = (m >= 0) ? (x + (size_t)m * 16) : zrow;
        const float* wk = Wt + (size_t)k * 16 * 32;
        f4 w0 = *(const f4*)(wk + (0 * 32 + co) * 4);
        f4 w1 = *(const f4*)(wk + (1 * 32 + co) * 4);
        f4 w2 = *(const f4*)(wk + (2 * 32 + co) * 4);
        f4 w3 = *(const f4*)(wk + (3 * 32 + co) * 4);
        f4 x0 = *(const f4*)(xr);
        f4 x1 = *(const f4*)(xr + 4);
        f4 x2 = *(const f4*)(xr + 8);
        f4 x3 = *(const f4*)(xr + 12);
        #pragma unroll
        for (int u = 0; u < 4; ++u) {
            a0 = fmaf(x0[u], w0[u], a0);
            a1 = fmaf(x1[u], w1[u], a1);
            a2 = fmaf(x2[u], w2[u], a2);
            a3 = fmaf(x3[u], w3[u], a3);
        }
    }
    if (j < N) out[(size_t)j * 32 + co] = (_Float16)((a0 + a1) + (a2 + a3));
}

// ---------------------------------------------------------------------------
// conv0t: concat(d1[*,64]h, s1[*,32]h) -> out[N0,2] fp32. ctz-union loop.
// ---------------------------------------------------------------------------
__global__ __launch_bounds__(256)
void sconv0t(const _Float16* __restrict__ d1, const _Float16* __restrict__ s1,
             const float* __restrict__ W /*[27,96,2]*/,
             const int* __restrict__ map, int N, float* __restrict__ out,
             const _Float16* __restrict__ zrh)
{
    const int tid  = threadIdx.x;
    const int lane = tid & 63;
    const int l32  = tid & 31;
    const int j    = blockIdx.x * 8 + (tid >> 5);

    int mk = (l32 < 27 && j < N) ? map[(size_t)l32 * N + j] : -1;
    const unsigned long long bal = __ballot(mk >= 0);
    unsigned int act = (unsigned int)((bal | (bal >> 32)) & 0x7FFFFFFu);

    float a0 = 0.f, a1 = 0.f;
    while (act) {
        const int k = (int)__builtin_ctz(act);
        act &= act - 1;
        const int m = __shfl(mk, (lane & 32) + k);
        const _Float16* p1 = (m >= 0) ? (d1 + (size_t)m * 64) : zrh;
        const _Float16* p2 = (m >= 0) ? (s1 + (size_t)m * 32) : zrh;
        const float* w = W + (size_t)k * 96 * 2;
        const float x0 = (float)p1[l32];
        const float x1 = (float)p1[l32 + 32];
        const float x2 = (float)p2[l32];
        a0 = fmaf(x0, w[l32 * 2 + 0], a0);
        a1 = fmaf(x0, w[l32 * 2 + 1], a1);
        a0 = fmaf(x1, w[(l32 + 32) * 2 + 0], a0);
        a1 = fmaf(x1, w[(l32 + 32) * 2 + 1], a1);
        a0 = fmaf(x2, w[(l32 + 64) * 2 + 0], a0);
        a1 = fmaf(x2, w[(l32 + 64) * 2 + 1], a1);
    }
    #pragma unroll
    for (int off = 1; off < 32; off <<= 1) {
        a0 += __shfl_xor(a0, off, 32);
        a1 += __shfl_xor(a1, off, 32);
    }
    if (l32 == 0 && j < N) {
        out[(size_t)j * 2 + 0] = a0;
        out[(size_t)j * 2 + 1] = a1;
    }
}

// ---------------------------------------------------------------------------
// BN pass 1 on half tensors
// ---------------------------------------------------------------------------
template<int C>
__global__ __launch_bounds__(256)
void bn_reduce_h(const _Float16* __restrict__ x, int N,
                 float* __restrict__ sums)
{
    constexpr int RG = 256 / C;
    const int tid = threadIdx.x;
    const int c   = tid % C;
    const int rg  = tid / C;
    float s = 0.f, s2 = 0.f;
    for (int j = blockIdx.x * RG + rg; j < N; j += gridDim.x * RG) {
        const float v = (float)x[(size_t)j * C + c];
        s += v;
        s2 += v * v;
    }
    __shared__ float sh[2 * 256];
    sh[tid] = s;
    sh[256 + tid] = s2;
    __syncthreads();
    for (int stride = 128; stride >= C; stride >>= 1) {
        if (tid < stride) {
            sh[tid] += sh[tid + stride];
            sh[256 + tid] += sh[256 + tid + stride];
        }
        __syncthreads();
    }
    if (tid < C) {
        atomicAdd(&sums[c], sh[tid]);
        atomicAdd(&sums[C + c], sh[256 + tid]);
    }
}

// ---------------------------------------------------------------------------
// BN pass 2 on half tensors
// ---------------------------------------------------------------------------
template<int C>
__global__ __launch_bounds__(256)
void bn_apply_h(_Float16* __restrict__ x, int N,
                const float* __restrict__ sums,
                const float* __restrict__ g, const float* __restrict__ b)
{
    const int tid = blockIdx.x * blockDim.x + threadIdx.x;
    const int c = tid % C;
    const float invN = 1.0f / (float)N;
    const float mean = sums[c] * invN;
    float var = sums[C + c] * invN - mean * mean;
    var = fmaxf(var, 0.f);
    const float sc = g[c] * rsqrtf(var + BN_EPS);
    const float sh = b[c] - mean * sc;
    const int rows_stride = (gridDim.x * blockDim.x) / C;
    for (int j = tid / C; j < N; j += rows_stride) {
        const size_t i = (size_t)j * C + c;
        const float v = fmaf((float)x[i], sc, sh);
        x[i] = (_Float16)(v > 0.f ? v : 0.f);
    }
}

// ---------------------------------------------------------------------------
extern "C" void kernel_launch(void* const* d_in, const int* in_sizes, int n_in,
                              void* d_out, int out_size, void* d_ws, size_t ws_size,
                              hipStream_t stream)
{
    const float* feats = (const float*)d_in[0];
    const float* W0  = (const float*)d_in[1];
    const float* g0  = (const float*)d_in[2];
    const float* b0  = (const float*)d_in[3];
    const float* W1  = (const float*)d_in[4];
    const float* g1  = (const float*)d_in[5];
    const float* b1  = (const float*)d_in[6];
    const float* W2  = (const float*)d_in[7];
    const float* g2  = (const float*)d_in[8];
    const float* b2  = (const float*)d_in[9];
    const float* W2t = (const float*)d_in[10];
    const float* g2t = (const float*)d_in[11];
    const float* b2t = (const float*)d_in[12];
    const float* W1t = (const float*)d_in[13];
    const float* g1t = (const float*)d_in[14];
    const float* b1t = (const float*)d_in[15];
    const float* W0t = (const float*)d_in[16];
    const int* map0  = (const int*)d_in[17];
    const int* map1  = (const int*)d_in[18];
    const int* map2  = (const int*)d_in[19];
    const int* map2t = (const int*)d_in[20];
    const int* map1t = (const int*)d_in[21];
    const int* map0t = (const int*)d_in[22];

    const int N0 = in_sizes[0] / 16;
    const int N1 = in_sizes[18] / 27;
    const int N2 = in_sizes[19] / 27;

    float* ws = (float*)d_ws;
    float* sums  = ws;          // 704 floats of BN accumulators
    float* sums0 = sums;        // 2*32
    float* sums1 = sums + 64;   // 2*64
    float* sums2 = sums + 192;  // 2*128
    float* sums3 = sums + 448;  // 2*64
    float* sums4 = sums + 576;  // 2*64
    float* zrow  = sums + 704;  // 128 zeroed floats (fp32 & f16 zero rows)
    float* Wt0   = zrow + 128;  // 27*16*32 fp32
    _Float16* hb = (_Float16*)(Wt0 + 27 * 16 * 32);
    _Float16* Wh1  = hb;                        // 27*32*64
    _Float16* Wh2  = Wh1 + 27 * 32 * 64;        // 27*64*128  (MFMA layout)
    _Float16* Wh2t = Wh2 + 27 * 64 * 128;       // 27*128*64  (MFMA layout)
    _Float16* Wh1t = Wh2t + 27 * 128 * 64;      // 27*128*64  (MFMA layout)
    _Float16* y0 = Wh1t + 27 * 128 * 64;        // [N0,32]  s1
    _Float16* y1 = y0 + (size_t)N0 * 32;        // [N1,64]  s2
    _Float16* y2 = y1 + (size_t)N1 * 64;        // [N2,128] s4
    _Float16* y3 = y2 + (size_t)N2 * 128;       // [N1,64]  d2
    _Float16* y4 = y3 + (size_t)N1 * 64;        // [N0,64]  d1
    int* mapT = (int*)(y4 + (size_t)N0 * 64);   // [Nmax,32] transposed map
    const _Float16* zrh = (const _Float16*)zrow;

    (void)hipMemsetAsync(sums, 0, (704 + 128) * sizeof(float), stream);

    // weight transposes (tiny)
    wtrans<16, 32><<<(27 * 4 * 32 + 255) / 256, 256, 0, stream>>>(W0, Wt0);
    wtrans_h<32, 64><<<(27 * 4 * 64 + 255) / 256, 256, 0, stream>>>(W1, Wh1);
    wtrans_mf<64, 128><<<(27 * 2 * 8 * 64 + 255) / 256, 256, 0, stream>>>(W2, Wh2);
    wtrans_mf<128, 64><<<(27 * 4 * 4 * 64 + 255) / 256, 256, 0, stream>>>(W2t, Wh2t);
    wtrans_mf<128, 64><<<(27 * 4 * 4 * 64 + 255) / 256, 256, 0, stream>>>(W1t, Wh1t);

    // block0: feats[N0,16] fp32 -> y0[N0,32] half
    sconv0<<<(N0 + 7) / 8, 256, 0, stream>>>(feats, Wt0, map0, N0, y0, zrow);
    bn_reduce_h<32><<<256, 256, 0, stream>>>(y0, N0, sums0);
    bn_apply_h<32><<<512, 256, 0, stream>>>(y0, N0, sums0, g0, b0);

    // block1 (SPARSE map): one wave per row (scalar dot2 path)
    map_transpose<<<(N1 + 255) / 256, 256, 0, stream>>>(map1, N1, mapT);
    sconv_r1<32, 32, 64><<<(N1 + 3) / 4, 256, 0, stream>>>(
        y0, nullptr, Wh1, mapT, N1, y1);
    bn_reduce_h<64><<<256, 256, 0, stream>>>(y1, N1, sums1);
    bn_apply_h<64><<<512, 256, 0, stream>>>(y1, N1, sums1, g1, b1);

    // block2: MFMA, 16 rows/wave
    sconv_mf<64, 64, 128><<<(N2 + 63) / 64, 256, 0, stream>>>(
        y1, nullptr, Wh2, map2, N2, y2, zrh);
    bn_reduce_h<128><<<256, 256, 0, stream>>>(y2, N2, sums2);
    bn_apply_h<128><<<512, 256, 0, stream>>>(y2, N2, sums2, g2, b2);

    // block2_tr: MFMA, 16 rows/wave
    sconv_mf<128, 128, 64><<<(N1 + 63) / 64, 256, 0, stream>>>(
        y2, nullptr, Wh2t, map2t, N1, y3, zrh);
    bn_reduce_h<64><<<256, 256, 0, stream>>>(y3, N1, sums3);
    bn_apply_h<64><<<512, 256, 0, stream>>>(y3, N1, sums3, g2t, b2t);

    // block1_tr: MFMA, 16 rows/wave, concat input (y3[64] ++ y1[64])
    sconv_mf<128, 64, 64><<<(N0 + 63) / 64, 256, 0, stream>>>(
        y3, y1, Wh1t, map1t, N0, y4, zrh);
    bn_reduce_h<64><<<256, 256, 0, stream>>>(y4, N0, sums4);
    bn_apply_h<64><<<512, 256, 0, stream>>>(y4, N0, sums4, g1t, b1t);

    // block0_tr: concat(d1,s1)[N0,96] -> out[N0,2] fp32
    sconv0t<<<(N0 + 7) / 8, 256, 0, stream>>>(y4, y0, W0t, map0t, N0,
                                              (float*)d_out, zrh);
}

// Round 4
// 943.381 us; speedup vs baseline: 1.2082x; 1.0320x over previous
//
#include <hip/hip_runtime.h>
#include <cstddef>
#include <cstdint>

#define BN_EPS 1e-5f

typedef float f4 __attribute__((ext_vector_type(4)));
typedef float f32x4 __attribute__((ext_vector_type(4)));
typedef _Float16 h2 __attribute__((ext_vector_type(2)));
typedef _Float16 h8 __attribute__((ext_vector_type(8)));

#if defined(__has_builtin)
#if __has_builtin(__builtin_amdgcn_fdot2)
#define DOT2(a, b, c) __builtin_amdgcn_fdot2((a), (b), (c), false)
#endif
#endif
#ifndef DOT2
#define DOT2(a, b, c) fmaf((float)(a)[1], (float)(b)[1], fmaf((float)(a)[0], (float)(b)[0], (c)))
#endif

// ---------------------------------------------------------------------------
// fp32 weight transpose (sconv0 only): W[27][CIN][COUT] -> Wt[k][ci/4][co][4]
// ---------------------------------------------------------------------------
template<int CIN, int COUT>
__global__ __launch_bounds__(256)
void wtrans(const float* __restrict__ W, float* __restrict__ Wt)
{
    const int t = blockIdx.x * 256 + threadIdx.x;
    constexpr int TOTAL = 27 * (CIN / 4) * COUT;
    if (t >= TOTAL) return;
    const int co = t % COUT;
    const int rest = t / COUT;
    const int c4 = rest % (CIN / 4);
    const int k  = rest / (CIN / 4);
    f4 v;
    #pragma unroll
    for (int u = 0; u < 4; ++u)
        v[u] = W[((size_t)k * CIN + c4 * 4 + u) * COUT + co];
    *(f4*)(Wt + (size_t)t * 4) = v;
}

// ---------------------------------------------------------------------------
// f16 weight transpose (sconv_r1): W[27][CIN][COUT] -> Wh[k][ci/8][co][8]
// ---------------------------------------------------------------------------
template<int CIN, int COUT>
__global__ __launch_bounds__(256)
void wtrans_h(const float* __restrict__ W, _Float16* __restrict__ Wh)
{
    const int t = blockIdx.x * 256 + threadIdx.x;
    constexpr int TOTAL = 27 * (CIN / 8) * COUT;
    if (t >= TOTAL) return;
    const int co = t % COUT;
    const int rest = t / COUT;
    const int t8 = rest % (CIN / 8);
    const int k  = rest / (CIN / 8);
    h8 v;
    #pragma unroll
    for (int u = 0; u < 8; ++u)
        v[u] = (_Float16)W[((size_t)k * CIN + t8 * 8 + u) * COUT + co];
    *(h8*)(Wh + (size_t)t * 8) = v;
}

// ---------------------------------------------------------------------------
// MFMA weight transform: W[27][CIN][COUT] fp32 -> B-fragment layout f16:
// Wm[((k*NT + t)*NC + ct)*64 + lane][8], where the h8 for `lane` holds
// B[kk][co] with kk = t*32 + (lane>>4)*8 + u, co = ct*16 + (lane&15).
// Matches the mfma_f32_16x16x32_f16 B operand slot layout.
// ---------------------------------------------------------------------------
template<int CIN, int COUT>
__global__ __launch_bounds__(256)
void wtrans_mf(const float* __restrict__ W, _Float16* __restrict__ Wm)
{
    constexpr int NT = CIN / 32;
    constexpr int NC = COUT / 16;
    const int t = blockIdx.x * 256 + threadIdx.x;
    constexpr int TOTAL = 27 * NT * NC * 64;
    if (t >= TOTAL) return;
    const int lane = t & 63;
    int rest = t >> 6;
    const int ct = rest % NC; rest /= NC;
    const int tt = rest % NT;
    const int k  = rest / NT;
    const int cin0 = tt * 32 + (lane >> 4) * 8;
    const int co   = ct * 16 + (lane & 15);
    h8 v;
    #pragma unroll
    for (int u = 0; u < 8; ++u)
        v[u] = (_Float16)W[((size_t)k * CIN + cin0 + u) * COUT + co];
    *(h8*)(Wm + (size_t)t * 8) = v;
}

// ---------------------------------------------------------------------------
// Map transpose: map[27][Nout] -> mapT[Nout][32] (k-major per row, -1 pad).
// ---------------------------------------------------------------------------
__global__ __launch_bounds__(256)
void map_transpose(const int* __restrict__ map, int Nout,
                   int* __restrict__ mapT)
{
    __shared__ int s[256][28];
    const int tid  = threadIdx.x;
    const int base = blockIdx.x * 256;
    const int j    = base + tid;
    for (int k = 0; k < 27; ++k)
        s[tid][k] = (j < Nout) ? map[(size_t)k * Nout + j] : -1;
    __syncthreads();
    for (int i = tid; i < 256 * 32; i += 256) {
        const int r = i >> 5, c = i & 31;
        if (base + r < Nout)
            mapT[(size_t)(base + r) * 32 + c] = (c < 27) ? s[r][c] : -1;
    }
}

// ---------------------------------------------------------------------------
// R=1 f16 sparse conv (SPARSE maps): one wave = one row.
// ---------------------------------------------------------------------------
template<int CIN, int CINA, int COUT>
__global__ __launch_bounds__(256)
void sconv_r1(const _Float16* __restrict__ xA, const _Float16* __restrict__ xB,
              const _Float16* __restrict__ Wh, const int* __restrict__ mapT,
              int Nout, _Float16* __restrict__ out)
{
    constexpr int CINB = CIN - CINA;
    constexpr int CPL  = COUT / 64;
    constexpr int NT   = CIN / 8;
    const int lane = threadIdx.x & 63;
    const int j    = blockIdx.x * 4 + (threadIdx.x >> 6);

    int mk = -1;
    if (j < Nout && lane < 32) mk = mapT[(size_t)j * 32 + lane];
    unsigned long long act = __ballot(mk >= 0);   // bits 0..26 only

    float acc[CPL];
    #pragma unroll
    for (int c = 0; c < CPL; ++c) acc[c] = 0.f;

    while (act) {
        const int k = (int)__builtin_ctzll(act);
        act &= act - 1;
        const int m = __builtin_amdgcn_readlane(mk, k);   // uniform SGPR

        const _Float16* pA = xA + (size_t)m * CINA;
        const _Float16* pB = nullptr;
        if constexpr (CINB > 0) pB = xB + (size_t)m * CINB;

        const _Float16* Wk = Wh + (size_t)k * NT * COUT * 8;

        #pragma unroll
        for (int t = 0; t < NT; ++t) {
            const int ci = t * 8;
            h8 wv[CPL];
            #pragma unroll
            for (int c = 0; c < CPL; ++c)
                wv[c] = *(const h8*)(Wk + ((size_t)t * COUT + c * 64 + lane) * 8);
            const _Float16* p;
            if constexpr (CINB > 0)
                p = (ci < CINA) ? (pA + ci) : (pB + (ci - CINA));
            else
                p = pA + ci;
            const h8 xv = *(const h8*)p;
            const h2* xp = (const h2*)&xv;
            #pragma unroll
            for (int q = 0; q < 4; ++q) {
                #pragma unroll
                for (int c = 0; c < CPL; ++c) {
                    const h2* wp = (const h2*)&wv[c];
                    acc[c] = DOT2(xp[q], wp[q], acc[c]);
                }
            }
        }
    }

    if (j < Nout) {
        #pragma unroll
        for (int c = 0; c < CPL; ++c)
            out[(size_t)j * COUT + c * 64 + lane] = (_Float16)acc[c];
    }
}

// ---------------------------------------------------------------------------
// MFMA sparse conv, round-4 SOFTWARE PIPELINE: one wave = 16 output rows.
// The 27x16 map tile (already in mk[] registers, k-major) is staged to LDS
// once, so the per-k per-lane gather row is an LDS read instead of a fresh
// global (L2) load at the head of every iteration's dependency chain. The
// while-loop is 1-deep pipelined: next k's m + A-fragments are prefetched
// into a second register buffer while the current k's MFMAs issue, hiding
// the ~400-cycle gather latency under compute.
// ---------------------------------------------------------------------------
template<int CIN, int CINA, int COUT>
__global__ __launch_bounds__(256)
void sconv_mf(const _Float16* __restrict__ xA, const _Float16* __restrict__ xB,
              const _Float16* __restrict__ Wm, const int* __restrict__ map,
              int Nout, _Float16* __restrict__ out,
              const _Float16* __restrict__ zrh)
{
    constexpr int CINB = CIN - CINA;
    constexpr int NT = CIN / 32;    // K chunks of 32
    constexpr int NC = COUT / 16;   // cout tiles of 16
    static_assert(CINA % 32 == 0, "CINA must be a multiple of 32");
    const int lane = threadIdx.x & 63;
    const int wave = threadIdx.x >> 6;
    const int row0 = (blockIdx.x * 4 + wave) * 16;

    // [r][k] layout: writes (fixed r, lanes k consecutive) conflict-free;
    // reads (fixed k, rrow stride 28 dwords) ~2-way + 4x broadcast -> free.
    __shared__ int smap[4][16][28];

    // lane k holds the 16 map entries of its k
    int mk[16];
    bool anyv = false;
    #pragma unroll
    for (int r = 0; r < 16; ++r) {
        const int j = row0 + r;
        mk[r] = (lane < 27 && j < Nout) ? map[(size_t)lane * Nout + j] : -1;
        anyv |= (mk[r] >= 0);
    }
    unsigned long long act = __ballot(anyv);

    if (lane < 27) {
        #pragma unroll
        for (int r = 0; r < 16; ++r)
            smap[wave][r][lane] = mk[r];
    }

    f32x4 acc[NC];
    #pragma unroll
    for (int c = 0; c < NC; ++c) acc[c] = (f32x4){0.f, 0.f, 0.f, 0.f};

    const int rrow = lane & 15;   // A row this lane gathers / D col
    const int kseg = lane >> 4;   // k segment

    // gather the A fragments for offset k into a[NT]
    auto loada = [&](int k, h8* a) {
        const int m = smap[wave][rrow][k];
        #pragma unroll
        for (int t = 0; t < NT; ++t) {
            const int cin0 = t * 32 + kseg * 8;
            const _Float16* pa;
            if (m >= 0) {
                if (CINB > 0 && t * 32 >= CINA)
                    pa = xB + (size_t)m * CINB + (cin0 - CINA);
                else
                    pa = xA + (size_t)m * CINA + cin0;
            } else {
                pa = zrh;
            }
            a[t] = *(const h8*)pa;
        }
    };
    auto compute = [&](int k, const h8* a) {
        const _Float16* Wk = Wm + ((size_t)k * NT * NC * 64 + lane) * 8;
        #pragma unroll
        for (int t = 0; t < NT; ++t) {
            #pragma unroll
            for (int c = 0; c < NC; ++c) {
                const h8 b = *(const h8*)(Wk + (size_t)(t * NC + c) * 64 * 8);
                acc[c] = __builtin_amdgcn_mfma_f32_16x16x32_f16(a[t], b, acc[c], 0, 0, 0);
            }
        }
    };

    h8 aC[NT], aN[NT];
    int kC = -1;
    if (act) {
        kC = (int)__builtin_ctzll(act);
        act &= act - 1;
        loada(kC, aC);
    }
    while (kC >= 0) {            // act is wave-uniform -> no divergence
        int kN = -1;
        if (act) {
            kN = (int)__builtin_ctzll(act);
            act &= act - 1;
            loada(kN, aN);       // prefetch next k under current MFMAs
        }
        compute(kC, aC);
        #pragma unroll
        for (int t = 0; t < NT; ++t) aC[t] = aN[t];
        kC = kN;
    }

    // D: lane (kseg,rrow), reg r -> row = kseg*4 + r, col = rrow
    #pragma unroll
    for (int c = 0; c < NC; ++c) {
        #pragma unroll
        for (int r = 0; r < 4; ++r) {
            const int j = row0 + kseg * 4 + r;
            if (j < Nout)
                out[(size_t)j * COUT + c * 16 + rrow] = (_Float16)acc[c][r];
        }
    }
}

// ---------------------------------------------------------------------------
// conv0: CIN=16 (fp32 feats), COUT=32 -> half out. 2 rows/wave, ctz-union.
// ---------------------------------------------------------------------------
__global__ __launch_bounds__(256)
void sconv0(const float* __restrict__ x, const float* __restrict__ Wt,
            const int* __restrict__ map, int N, _Float16* __restrict__ out,
            const float* __restrict__ zrow)
{
    const int tid  = threadIdx.x;
    const int lane = tid & 63;
    const int l32  = tid & 31;
    const int co   = l32;
    const int j    = blockIdx.x * 8 + (tid >> 5);

    int mk = (l32 < 27 && j < N) ? map[(size_t)l32 * N + j] : -1;
    const unsigned long long bal = __ballot(mk >= 0);
    unsigned int act = (unsigned int)((bal | (bal >> 32)) & 0x7FFFFFFu);

    float a0 = 0.f, a1 = 0.f, a2 = 0.f, a3 = 0.f;
    while (act) {
        const int k = (int)__builtin_ctz(act);
        act &= act - 1;
        const int m = __shfl(mk, (lane & 32) + k);
        const float* xr = (m >= 0) ? (x + (size_t)m * 16) : zrow;
        const float* wk = Wt + (size_t)k * 16 * 32;
        f4 w0 = *(const f4*)(wk + (0 * 32 + co) * 4);
        f4 w1 = *(const f4*)(wk + (1 * 32 + co) * 4);
        f4 w2 = *(const f4*)(wk + (2 * 32 + co) * 4);
        f4 w3 = *(const f4*)(wk + (3 * 32 + co) * 4);
        f4 x0 = *(const f4*)(xr);
        f4 x1 = *(const f4*)(xr + 4);
        f4 x2 = *(const f4*)(xr + 8);
        f4 x3 = *(const f4*)(xr + 12);
        #pragma unroll
        for (int u = 0; u < 4; ++u) {
            a0 = fmaf(x0[u], w0[u], a0);
            a1 = fmaf(x1[u], w1[u], a1);
            a2 = fmaf(x2[u], w2[u], a2);
            a3 = fmaf(x3[u], w3[u], a3);
        }
    }
    if (j < N) out[(size_t)j * 32 + co] = (_Float16)((a0 + a1) + (a2 + a3));
}

// ---------------------------------------------------------------------------
// conv0t: concat(d1[*,64]h, s1[*,32]h) -> out[N0,2] fp32. ctz-union loop.
// ---------------------------------------------------------------------------
__global__ __launch_bounds__(256)
void sconv0t(const _Float16* __restrict__ d1, const _Float16* __restrict__ s1,
             const float* __restrict__ W /*[27,96,2]*/,
             const int* __restrict__ map, int N, float* __restrict__ out,
             const _Float16* __restrict__ zrh)
{
    const int tid  = threadIdx.x;
    const int lane = tid & 63;
    const int l32  = tid & 31;
    const int j    = blockIdx.x * 8 + (tid >> 5);

    int mk = (l32 < 27 && j < N) ? map[(size_t)l32 * N + j] : -1;
    const unsigned long long bal = __ballot(mk >= 0);
    unsigned int act = (unsigned int)((bal | (bal >> 32)) & 0x7FFFFFFu);

    float a0 = 0.f, a1 = 0.f;
    while (act) {
        const int k = (int)__builtin_ctz(act);
        act &= act - 1;
        const int m = __shfl(mk, (lane & 32) + k);
        const _Float16* p1 = (m >= 0) ? (d1 + (size_t)m * 64) : zrh;
        const _Float16* p2 = (m >= 0) ? (s1 + (size_t)m * 32) : zrh;
        const float* w = W + (size_t)k * 96 * 2;
        const float x0 = (float)p1[l32];
        const float x1 = (float)p1[l32 + 32];
        const float x2 = (float)p2[l32];
        a0 = fmaf(x0, w[l32 * 2 + 0], a0);
        a1 = fmaf(x0, w[l32 * 2 + 1], a1);
        a0 = fmaf(x1, w[(l32 + 32) * 2 + 0], a0);
        a1 = fmaf(x1, w[(l32 + 32) * 2 + 1], a1);
        a0 = fmaf(x2, w[(l32 + 64) * 2 + 0], a0);
        a1 = fmaf(x2, w[(l32 + 64) * 2 + 1], a1);
    }
    #pragma unroll
    for (int off = 1; off < 32; off <<= 1) {
        a0 += __shfl_xor(a0, off, 32);
        a1 += __shfl_xor(a1, off, 32);
    }
    if (l32 == 0 && j < N) {
        out[(size_t)j * 2 + 0] = a0;
        out[(size_t)j * 2 + 1] = a1;
    }
}

// ---------------------------------------------------------------------------
// BN pass 1 on half tensors
// ---------------------------------------------------------------------------
template<int C>
__global__ __launch_bounds__(256)
void bn_reduce_h(const _Float16* __restrict__ x, int N,
                 float* __restrict__ sums)
{
    constexpr int RG = 256 / C;
    const int tid = threadIdx.x;
    const int c   = tid % C;
    const int rg  = tid / C;
    float s = 0.f, s2 = 0.f;
    for (int j = blockIdx.x * RG + rg; j < N; j += gridDim.x * RG) {
        const float v = (float)x[(size_t)j * C + c];
        s += v;
        s2 += v * v;
    }
    __shared__ float sh[2 * 256];
    sh[tid] = s;
    sh[256 + tid] = s2;
    __syncthreads();
    for (int stride = 128; stride >= C; stride >>= 1) {
        if (tid < stride) {
            sh[tid] += sh[tid + stride];
            sh[256 + tid] += sh[256 + tid + stride];
        }
        __syncthreads();
    }
    if (tid < C) {
        atomicAdd(&sums[c], sh[tid]);
        atomicAdd(&sums[C + c], sh[256 + tid]);
    }
}

// ---------------------------------------------------------------------------
// BN pass 2 on half tensors
// ---------------------------------------------------------------------------
template<int C>
__global__ __launch_bounds__(256)
void bn_apply_h(_Float16* __restrict__ x, int N,
                const float* __restrict__ sums,
                const float* __restrict__ g, const float* __restrict__ b)
{
    const int tid = blockIdx.x * blockDim.x + threadIdx.x;
    const int c = tid % C;
    const float invN = 1.0f / (float)N;
    const float mean = sums[c] * invN;
    float var = sums[C + c] * invN - mean * mean;
    var = fmaxf(var, 0.f);
    const float sc = g[c] * rsqrtf(var + BN_EPS);
    const float sh = b[c] - mean * sc;
    const int rows_stride = (gridDim.x * blockDim.x) / C;
    for (int j = tid / C; j < N; j += rows_stride) {
        const size_t i = (size_t)j * C + c;
        const float v = fmaf((float)x[i], sc, sh);
        x[i] = (_Float16)(v > 0.f ? v : 0.f);
    }
}

// ---------------------------------------------------------------------------
extern "C" void kernel_launch(void* const* d_in, const int* in_sizes, int n_in,
                              void* d_out, int out_size, void* d_ws, size_t ws_size,
                              hipStream_t stream)
{
    const float* feats = (const float*)d_in[0];
    const float* W0  = (const float*)d_in[1];
    const float* g0  = (const float*)d_in[2];
    const float* b0  = (const float*)d_in[3];
    const float* W1  = (const float*)d_in[4];
    const float* g1  = (const float*)d_in[5];
    const float* b1  = (const float*)d_in[6];
    const float* W2  = (const float*)d_in[7];
    const float* g2  = (const float*)d_in[8];
    const float* b2  = (const float*)d_in[9];
    const float* W2t = (const float*)d_in[10];
    const float* g2t = (const float*)d_in[11];
    const float* b2t = (const float*)d_in[12];
    const float* W1t = (const float*)d_in[13];
    const float* g1t = (const float*)d_in[14];
    const float* b1t = (const float*)d_in[15];
    const float* W0t = (const float*)d_in[16];
    const int* map0  = (const int*)d_in[17];
    const int* map1  = (const int*)d_in[18];
    const int* map2  = (const int*)d_in[19];
    const int* map2t = (const int*)d_in[20];
    const int* map1t = (const int*)d_in[21];
    const int* map0t = (const int*)d_in[22];

    const int N0 = in_sizes[0] / 16;
    const int N1 = in_sizes[18] / 27;
    const int N2 = in_sizes[19] / 27;

    float* ws = (float*)d_ws;
    float* sums  = ws;          // 704 floats of BN accumulators
    float* sums0 = sums;        // 2*32
    float* sums1 = sums + 64;   // 2*64
    float* sums2 = sums + 192;  // 2*128
    float* sums3 = sums + 448;  // 2*64
    float* sums4 = sums + 576;  // 2*64
    float* zrow  = sums + 704;  // 128 zeroed floats (fp32 & f16 zero rows)
    float* Wt0   = zrow + 128;  // 27*16*32 fp32
    _Float16* hb = (_Float16*)(Wt0 + 27 * 16 * 32);
    _Float16* Wh1  = hb;                        // 27*32*64
    _Float16* Wh2  = Wh1 + 27 * 32 * 64;        // 27*64*128  (MFMA layout)
    _Float16* Wh2t = Wh2 + 27 * 64 * 128;       // 27*128*64  (MFMA layout)
    _Float16* Wh1t = Wh2t + 27 * 128 * 64;      // 27*128*64  (MFMA layout)
    _Float16* y0 = Wh1t + 27 * 128 * 64;        // [N0,32]  s1
    _Float16* y1 = y0 + (size_t)N0 * 32;        // [N1,64]  s2
    _Float16* y2 = y1 + (size_t)N1 * 64;        // [N2,128] s4
    _Float16* y3 = y2 + (size_t)N2 * 128;       // [N1,64]  d2
    _Float16* y4 = y3 + (size_t)N1 * 64;        // [N0,64]  d1
    int* mapT = (int*)(y4 + (size_t)N0 * 64);   // [Nmax,32] transposed map
    const _Float16* zrh = (const _Float16*)zrow;

    (void)hipMemsetAsync(sums, 0, (704 + 128) * sizeof(float), stream);

    // weight transposes (tiny)
    wtrans<16, 32><<<(27 * 4 * 32 + 255) / 256, 256, 0, stream>>>(W0, Wt0);
    wtrans_h<32, 64><<<(27 * 4 * 64 + 255) / 256, 256, 0, stream>>>(W1, Wh1);
    wtrans_mf<64, 128><<<(27 * 2 * 8 * 64 + 255) / 256, 256, 0, stream>>>(W2, Wh2);
    wtrans_mf<128, 64><<<(27 * 4 * 4 * 64 + 255) / 256, 256, 0, stream>>>(W2t, Wh2t);
    wtrans_mf<128, 64><<<(27 * 4 * 4 * 64 + 255) / 256, 256, 0, stream>>>(W1t, Wh1t);

    // block0: feats[N0,16] fp32 -> y0[N0,32] half
    sconv0<<<(N0 + 7) / 8, 256, 0, stream>>>(feats, Wt0, map0, N0, y0, zrow);
    bn_reduce_h<32><<<256, 256, 0, stream>>>(y0, N0, sums0);
    bn_apply_h<32><<<512, 256, 0, stream>>>(y0, N0, sums0, g0, b0);

    // block1 (SPARSE map): one wave per row (scalar dot2 path)
    map_transpose<<<(N1 + 255) / 256, 256, 0, stream>>>(map1, N1, mapT);
    sconv_r1<32, 32, 64><<<(N1 + 3) / 4, 256, 0, stream>>>(
        y0, nullptr, Wh1, mapT, N1, y1);
    bn_reduce_h<64><<<256, 256, 0, stream>>>(y1, N1, sums1);
    bn_apply_h<64><<<512, 256, 0, stream>>>(y1, N1, sums1, g1, b1);

    // block2: MFMA pipelined, 16 rows/wave
    sconv_mf<64, 64, 128><<<(N2 + 63) / 64, 256, 0, stream>>>(
        y1, nullptr, Wh2, map2, N2, y2, zrh);
    bn_reduce_h<128><<<256, 256, 0, stream>>>(y2, N2, sums2);
    bn_apply_h<128><<<512, 256, 0, stream>>>(y2, N2, sums2, g2, b2);

    // block2_tr: MFMA pipelined, 16 rows/wave
    sconv_mf<128, 128, 64><<<(N1 + 63) / 64, 256, 0, stream>>>(
        y2, nullptr, Wh2t, map2t, N1, y3, zrh);
    bn_reduce_h<64><<<256, 256, 0, stream>>>(y3, N1, sums3);
    bn_apply_h<64><<<512, 256, 0, stream>>>(y3, N1, sums3, g2t, b2t);

    // block1_tr: MFMA pipelined, 16 rows/wave, concat input (y3[64] ++ y1[64])
    sconv_mf<128, 64, 64><<<(N0 + 63) / 64, 256, 0, stream>>>(
        y3, y1, Wh1t, map1t, N0, y4, zrh);
    bn_reduce_h<64><<<256, 256, 0, stream>>>(y4, N0, sums4);
    bn_apply_h<64><<<512, 256, 0, stream>>>(y4, N0, sums4, g1t, b1t);

    // block0_tr: concat(d1,s1)[N0,96] -> out[N0,2] fp32
    sconv0t<<<(N0 + 7) / 8, 256, 0, stream>>>(y4, y0, W0t, map0t, N0,
                                              (float*)d_out, zrh);
}